// Round 1
// baseline (7030.019 us; speedup 1.0000x reference)
//
#include <hip/hip_runtime.h>

#define EPS_ 1e-5f
#define HW_ 16384

__device__ __forceinline__ float sigmoidf_(float v) { return 1.f / (1.f + __expf(-v)); }

// ---------------------------------------------------------------- gate stage 1
__global__ void gap_partial_kernel(const float* __restrict__ x, float* __restrict__ partial) {
  int bc = blockIdx.x;  // b*256 + c, 2048 blocks
  const float4* p = (const float4*)(x + (size_t)bc * HW_);
  float s = 0.f;
  for (int i = threadIdx.x; i < HW_ / 4; i += 256) {
    float4 v = p[i];
    s += (v.x + v.y) + (v.z + v.w);
  }
#pragma unroll
  for (int off = 32; off; off >>= 1) s += __shfl_down(s, off, 64);
  __shared__ float red[4];
  if ((threadIdx.x & 63) == 0) red[threadIdx.x >> 6] = s;
  __syncthreads();
  if (threadIdx.x == 0) partial[bc] = (red[0] + red[1]) + (red[2] + red[3]);
}

// ---------------------------------------------------------------- gate stage 2
__global__ void gate_kernel(const float* __restrict__ partial, const float* __restrict__ gw,
                            const float* __restrict__ gb, float* __restrict__ gout) {
  int b = blockIdx.x, t = threadIdx.x;
  float s = partial[b * 256 + t] * gw[t];
#pragma unroll
  for (int off = 32; off; off >>= 1) s += __shfl_down(s, off, 64);
  __shared__ float red[4];
  if ((t & 63) == 0) red[t >> 6] = s;
  __syncthreads();
  if (t == 0) {
    float tot = (red[0] + red[1]) + (red[2] + red[3]);
    gout[b] = sigmoidf_(tot * (1.f / 16384.f) + gb[0]);
  }
}

// ------------------------------------------- grouped conv + BN + SiLU + 1x1 + softmax
// grid: 8x8 tiles x 8 batches = 512 blocks; block = 256 threads = 16x16 pixels.
// h is never materialized: the 25 1x1-conv accumulators live in registers while
// the 32 groups stream through LDS.
__global__ __launch_bounds__(256) void kernelgen_kernel(
    const float* __restrict__ x, const float* __restrict__ w1, const float* __restrict__ b1,
    const float* __restrict__ bng, const float* __restrict__ bnb, const float* __restrict__ bnm,
    const float* __restrict__ bnv, const float* __restrict__ w2, const float* __restrict__ b2,
    float* __restrict__ kern) {
  int blk = blockIdx.x;
  int bx = blk & 7, by = (blk >> 3) & 7, b = blk >> 6;
  int lx = threadIdx.x & 15, ly = threadIdx.x >> 4;
  __shared__ float xs[8 * 324];  // 8 ch x 18x18 (halo 1)
  float acc[25];
#pragma unroll
  for (int n = 0; n < 25; ++n) acc[n] = b2[n];

  for (int g = 0; g < 32; ++g) {
    __syncthreads();
    for (int i = threadIdx.x; i < 8 * 324; i += 256) {
      int ch = i / 324, r = i - ch * 324;
      int yy = by * 16 + r / 18 - 1, xx = bx * 16 + (r % 18) - 1;
      float v = 0.f;
      if (yy >= 0 && yy < 128 && xx >= 0 && xx < 128)
        v = x[(((size_t)b * 256 + g * 8 + ch) << 14) + yy * 128 + xx];
      xs[i] = v;
    }
    __syncthreads();
    float h[8];
#pragma unroll
    for (int o = 0; o < 8; ++o) h[o] = b1[g * 8 + o];
#pragma unroll
    for (int ic = 0; ic < 8; ++ic) {
      float xv[9];
#pragma unroll
      for (int t = 0; t < 9; ++t)
        xv[t] = xs[ic * 324 + (ly + t / 3) * 18 + lx + (t % 3)];
#pragma unroll
      for (int o = 0; o < 8; ++o) {
        const float* wp = w1 + ((g * 8 + o) * 8 + ic) * 9;  // wave-uniform -> s_load
#pragma unroll
        for (int t = 0; t < 9; ++t) h[o] = fmaf(xv[t], wp[t], h[o]);
      }
    }
#pragma unroll
    for (int o = 0; o < 8; ++o) {
      int c = g * 8 + o;
      float scale = bng[c] * rsqrtf(bnv[c] + EPS_);
      float hb = (h[o] - bnm[c]) * scale + bnb[c];
      float sv = hb * sigmoidf_(hb);
#pragma unroll
      for (int n = 0; n < 25; ++n) acc[n] = fmaf(sv, w2[n * 256 + c], acc[n]);
    }
  }
  // softmax over 25
  float m = acc[0];
#pragma unroll
  for (int n = 1; n < 25; ++n) m = fmaxf(m, acc[n]);
  float sum = 0.f;
#pragma unroll
  for (int n = 0; n < 25; ++n) { acc[n] = __expf(acc[n] - m); sum += acc[n]; }
  float inv = 1.f / sum;
  int gy = by * 16 + ly, gx = bx * 16 + lx;
  size_t base = (((size_t)b * 25) << 14) + gy * 128 + gx;
#pragma unroll
  for (int n = 0; n < 25; ++n) kern[base + (n << 14)] = acc[n] * inv;
}

// ------------------------------------------- dense conv + BN + SiLU + CARAFE + blend
// grid: 16 ocb (fastest, shares x tile in L2) x 8 bx x 4 by x 8 b = 4096 blocks.
// block = 256 threads; tile = 32h x 16w pixels, 2 px/thread (adjacent rows) so each
// wave-uniform weight s_load feeds 2 FMAs (scalar pipe is shared by 4 SIMDs).
__global__ __launch_bounds__(256) void dense_carafe_kernel(
    const float* __restrict__ x, const float* __restrict__ bw, const float* __restrict__ bb,
    const float* __restrict__ bng, const float* __restrict__ bnb, const float* __restrict__ bnm,
    const float* __restrict__ bnv, const float* __restrict__ kern, const float* __restrict__ gq,
    float* __restrict__ out) {
  int blk = blockIdx.x;
  int ocb = blk & 15;
  int rest = blk >> 4;
  int bx = rest & 7;
  int by = (rest >> 3) & 3;
  int b = rest >> 5;
  int lx = threadIdx.x & 15, lyp = threadIdx.x >> 4;
  __shared__ float lds[5760];  // conv stage: 8*612 (34x18); epilogue: 8*720 (36x20)
  float acc0[16], acc1[16];
#pragma unroll
  for (int o = 0; o < 16; ++o) { acc0[o] = 0.f; acc1[o] = 0.f; }

  const int y0 = 2 * lyp;  // local row of this thread's first pixel
  for (int cc = 0; cc < 32; ++cc) {
    __syncthreads();
    for (int i = threadIdx.x; i < 8 * 612; i += 256) {
      int ch = i / 612, r = i - ch * 612;
      int yy = by * 32 + r / 18 - 1, xx = bx * 16 + (r % 18) - 1;
      float v = 0.f;
      if (yy >= 0 && yy < 128 && xx >= 0 && xx < 128)
        v = x[(((size_t)b * 256 + cc * 8 + ch) << 14) + yy * 128 + xx];
      lds[i] = v;
    }
    __syncthreads();
#pragma unroll
    for (int ic = 0; ic < 8; ++ic) {
      float xv[4][3];
#pragma unroll
      for (int r = 0; r < 4; ++r)
#pragma unroll
        for (int c3 = 0; c3 < 3; ++c3)
          xv[r][c3] = lds[ic * 612 + (y0 + r) * 18 + lx + c3];
#pragma unroll
      for (int o = 0; o < 16; ++o) {
        const float* wp = bw + (((ocb * 16 + o) * 256) + cc * 8 + ic) * 9;  // uniform -> s_load
#pragma unroll
        for (int kh = 0; kh < 3; ++kh)
#pragma unroll
          for (int kw = 0; kw < 3; ++kw) {
            float w = wp[kh * 3 + kw];
            acc0[o] = fmaf(xv[kh][kw], w, acc0[o]);
            acc1[o] = fmaf(xv[kh + 1][kw], w, acc1[o]);
          }
      }
    }
  }
  // BN + SiLU -> static values (in place)
#pragma unroll
  for (int o = 0; o < 16; ++o) {
    int c = ocb * 16 + o;
    float scale = bng[c] * rsqrtf(bnv[c] + EPS_);
    float bias = bnb[c] + (bb[c] - bnm[c]) * scale;
    float h0 = acc0[o] * scale + bias;
    float h1 = acc1[o] * scale + bias;
    acc0[o] = h0 * sigmoidf_(h0);
    acc1[o] = h1 * sigmoidf_(h1);
  }
  float gv = gq[b];
  int gybase = by * 32, gxbase = bx * 16;
#pragma unroll
  for (int half = 0; half < 2; ++half) {
    __syncthreads();
    for (int i = threadIdx.x; i < 8 * 720; i += 256) {
      int ch = i / 720, r = i - ch * 720;
      int yy = gybase + r / 20 - 2, xx = gxbase + (r % 20) - 2;
      yy = yy < 0 ? -yy : (yy > 127 ? 254 - yy : yy);  // reflect pad
      xx = xx < 0 ? -xx : (xx > 127 ? 254 - xx : xx);
      lds[i] = x[(((size_t)b * 256 + ocb * 16 + half * 8 + ch) << 14) + yy * 128 + xx];
    }
    __syncthreads();
#pragma unroll
    for (int px = 0; px < 2; ++px) {
      int yloc = y0 + px;
      int gy = gybase + yloc, gx = gxbase + lx;
      float kv[25];
      size_t kb = (((size_t)b * 25) << 14) + gy * 128 + gx;
#pragma unroll
      for (int n = 0; n < 25; ++n) kv[n] = kern[kb + (n << 14)];
#pragma unroll
      for (int o8 = 0; o8 < 8; ++o8) {
        float car = 0.f;
#pragma unroll
        for (int n = 0; n < 25; ++n) {
          int ki = n / 5, kj = n - ki * 5;
          car = fmaf(lds[o8 * 720 + (yloc + ki) * 20 + lx + kj], kv[n], car);
        }
        float st = (px == 0) ? acc0[half * 8 + o8] : acc1[half * 8 + o8];
        out[(((size_t)b * 256 + ocb * 16 + half * 8 + o8) << 14) + gy * 128 + gx] =
            gv * car + (1.f - gv) * st;
      }
    }
  }
}

// ---------------------------------------------------------------- launcher
extern "C" void kernel_launch(void* const* d_in, const int* in_sizes, int n_in,
                              void* d_out, int out_size, void* d_ws, size_t ws_size,
                              hipStream_t stream) {
  const float* x      = (const float*)d_in[0];
  const float* ke_w1  = (const float*)d_in[1];
  const float* ke_b1  = (const float*)d_in[2];
  const float* ke_bng = (const float*)d_in[3];
  const float* ke_bnb = (const float*)d_in[4];
  const float* ke_bnm = (const float*)d_in[5];
  const float* ke_bnv = (const float*)d_in[6];
  const float* ke_w2  = (const float*)d_in[7];
  const float* ke_b2  = (const float*)d_in[8];
  const float* bs_w   = (const float*)d_in[9];
  const float* bs_b   = (const float*)d_in[10];
  const float* bs_bng = (const float*)d_in[11];
  const float* bs_bnb = (const float*)d_in[12];
  const float* bs_bnm = (const float*)d_in[13];
  const float* bs_bnv = (const float*)d_in[14];
  const float* g_w    = (const float*)d_in[15];
  const float* g_b    = (const float*)d_in[16];
  float* outp = (float*)d_out;

  float* ws      = (float*)d_ws;
  float* kern    = ws;               // 8*25*16384 = 3,276,800 floats
  float* partial = ws + 3276800;     // 2048 floats
  float* gout    = partial + 2048;   // 8 floats

  gap_partial_kernel<<<2048, 256, 0, stream>>>(x, partial);
  gate_kernel<<<8, 256, 0, stream>>>(partial, g_w, g_b, gout);
  kernelgen_kernel<<<512, 256, 0, stream>>>(x, ke_w1, ke_b1, ke_bng, ke_bnb, ke_bnm,
                                            ke_bnv, ke_w2, ke_b2, kern);
  dense_carafe_kernel<<<4096, 256, 0, stream>>>(x, bs_w, bs_b, bs_bng, bs_bnb, bs_bnm,
                                                bs_bnv, kern, gout, outp);
}

// Round 2
// 1260.011 us; speedup vs baseline: 5.5793x; 5.5793x over previous
//
#include <hip/hip_runtime.h>

#define EPS_ 1e-5f

typedef __attribute__((ext_vector_type(8))) short bf16x8;
typedef __attribute__((ext_vector_type(8))) unsigned short u16x8;
typedef __attribute__((ext_vector_type(4))) float f32x4;

__device__ __forceinline__ float sigmoidf_(float v) { return 1.f / (1.f + __expf(-v)); }

__device__ __forceinline__ unsigned short f2bf(float f) {
  unsigned int u = __float_as_uint(f);
  u += 0x7fff + ((u >> 16) & 1);  // RNE
  return (unsigned short)(u >> 16);
}
__device__ __forceinline__ float bf2f(unsigned short h) {
  return __uint_as_float(((unsigned int)h) << 16);
}

// ---------------------------------------------------------------- gate stage 1
__global__ void gap_partial_kernel(const float* __restrict__ x, float* __restrict__ partial) {
  int bc = blockIdx.x;
  const float4* p = (const float4*)(x + (size_t)bc * 16384);
  float s = 0.f;
  for (int i = threadIdx.x; i < 4096; i += 256) {
    float4 v = p[i];
    s += (v.x + v.y) + (v.z + v.w);
  }
#pragma unroll
  for (int off = 32; off; off >>= 1) s += __shfl_down(s, off, 64);
  __shared__ float red[4];
  if ((threadIdx.x & 63) == 0) red[threadIdx.x >> 6] = s;
  __syncthreads();
  if (threadIdx.x == 0) partial[bc] = (red[0] + red[1]) + (red[2] + red[3]);
}

// ---------------------------------------------------------------- gate stage 2
__global__ void gate_kernel(const float* __restrict__ partial, const float* __restrict__ gw,
                            const float* __restrict__ gb, float* __restrict__ gout) {
  int b = blockIdx.x, t = threadIdx.x;
  float s = partial[b * 256 + t] * gw[t];
#pragma unroll
  for (int off = 32; off; off >>= 1) s += __shfl_down(s, off, 64);
  __shared__ float red[4];
  if ((t & 63) == 0) red[t >> 6] = s;
  __syncthreads();
  if (t == 0) {
    float tot = (red[0] + red[1]) + (red[2] + red[3]);
    gout[b] = sigmoidf_(tot * (1.f / 16384.f) + gb[0]);
  }
}

// ---------------------------------------------------------------- weight transform
// wT[((cb*9+tap)*256 + oc)*32 + c] = bf16(bs_w[(oc*256 + cb*32 + c)*9 + tap])
__global__ void wtrans_kernel(const float* __restrict__ w, unsigned short* __restrict__ wT) {
  int n = blockIdx.x * 256 + threadIdx.x;  // 589824
  int c = n & 31, oc = (n >> 5) & 255, t9 = n >> 13;
  int cb = t9 / 9, tap = t9 - cb * 9;
  wT[n] = f2bf(w[(oc * 256 + cb * 32 + c) * 9 + tap]);
}

// ---------------------------------------------------------------- grouped conv -> h (bf16)
// grid: 32 groups x 16 px-tiles(32x32) x 8 b = 4096 blocks
__global__ __launch_bounds__(256) void gconv_kernel(
    const float* __restrict__ x, const float* __restrict__ w1, const float* __restrict__ b1,
    const float* __restrict__ bng, const float* __restrict__ bnb, const float* __restrict__ bnm,
    const float* __restrict__ bnv, unsigned short* __restrict__ h) {
  int blk = blockIdx.x;
  int g = blk & 31, t16 = (blk >> 5) & 15, b = blk >> 9;
  int px0 = (t16 & 3) * 32, py0 = (t16 >> 2) * 32;
  int lx = threadIdx.x & 31, ly0 = threadIdx.x >> 5;
  __shared__ float xs[8 * 1156];  // 8 ch x 34x34
  for (int i = threadIdx.x; i < 8 * 1156; i += 256) {
    int ch = i / 1156, r = i - ch * 1156;
    int yy = py0 + r / 34 - 1, xx = px0 + (r % 34) - 1;
    float v = 0.f;
    if ((unsigned)yy < 128u && (unsigned)xx < 128u)
      v = x[(((size_t)b * 256 + g * 8 + ch) << 14) + yy * 128 + xx];
    xs[i] = v;
  }
  __syncthreads();
  const float* wg = w1 + g * 8 * 72;  // [o][ic][9], uniform
#pragma unroll
  for (int it = 0; it < 4; ++it) {
    int py = ly0 + 8 * it;
    float ha[8];
#pragma unroll
    for (int o = 0; o < 8; ++o) ha[o] = b1[g * 8 + o];
#pragma unroll
    for (int ic = 0; ic < 8; ++ic) {
      float xv[9];
#pragma unroll
      for (int t = 0; t < 9; ++t)
        xv[t] = xs[ic * 1156 + (py + t / 3) * 34 + lx + (t % 3)];
#pragma unroll
      for (int o = 0; o < 8; ++o) {
        const float* wp = wg + o * 72 + ic * 9;
#pragma unroll
        for (int t = 0; t < 9; ++t) ha[o] = fmaf(xv[t], wp[t], ha[o]);
      }
    }
#pragma unroll
    for (int o = 0; o < 8; ++o) {
      int c = g * 8 + o;
      float scale = bng[c] * rsqrtf(bnv[c] + EPS_);
      float hb = (ha[o] - bnm[c]) * scale + bnb[c];
      float sv = hb * sigmoidf_(hb);
      h[(((size_t)b * 256 + c) << 14) + (py0 + py) * 128 + px0 + lx] = f2bf(sv);
    }
  }
}

// ---------------------------------------------------------------- 1x1 conv + softmax -> kern
__global__ __launch_bounds__(256) void k1x1_kernel(
    const unsigned short* __restrict__ h, const float* __restrict__ w2,
    const float* __restrict__ b2, float* __restrict__ kern) {
  __shared__ float w2s[6400];  // [n][ch]
  for (int i = threadIdx.x; i < 6400; i += 256) w2s[i] = w2[i];
  __syncthreads();
  int pix = blockIdx.x * 256 + threadIdx.x;  // 512 blocks
  int b = pix >> 14, p = pix & 16383;
  float acc[25];
#pragma unroll
  for (int n = 0; n < 25; ++n) acc[n] = b2[n];
  const unsigned short* hp = h + ((size_t)b << 22) + p;
  for (int ch = 0; ch < 256; ch += 2) {
    float h0 = bf2f(hp[(size_t)ch << 14]);
    float h1 = bf2f(hp[(size_t)(ch + 1) << 14]);
#pragma unroll
    for (int n = 0; n < 25; ++n) {
      float2 w = *(const float2*)&w2s[n * 256 + ch];
      acc[n] = fmaf(h1, w.y, fmaf(h0, w.x, acc[n]));
    }
  }
  float m = acc[0];
#pragma unroll
  for (int n = 1; n < 25; ++n) m = fmaxf(m, acc[n]);
  float sum = 0.f;
#pragma unroll
  for (int n = 0; n < 25; ++n) { acc[n] = __expf(acc[n] - m); sum += acc[n]; }
  float inv = 1.f / sum;
  size_t base = (((size_t)b * 25) << 14) + p;
#pragma unroll
  for (int n = 0; n < 25; ++n) kern[base + ((size_t)n << 14)] = acc[n] * inv;
}

// ---------------------------------------------------------------- dense conv via MFMA
// M=128 px (one image row) x N=128 oc per block; K = 8 cb x (9 taps x 32 ch).
// grid: ocb(2, fastest: shares x rows in L2) x y(128) x b(8) = 2048 blocks.
#define XPS 40               // bf16 per px in LDS (32 ch + 8 pad)
#define XRS (130 * XPS)      // row stride 5200
__global__ __launch_bounds__(256) void conv_mfma_kernel(
    const float* __restrict__ x, const unsigned short* __restrict__ wT,
    const float* __restrict__ bb, const float* __restrict__ bng,
    const float* __restrict__ bnb, const float* __restrict__ bnm,
    const float* __restrict__ bnv, unsigned short* __restrict__ staticbf) {
  int blk = blockIdx.x;
  int ocb = blk & 1, y = (blk >> 1) & 127, b = blk >> 8;
  int tid = threadIdx.x, lane = tid & 63, wid = tid >> 6;
  int wy = wid >> 1, wx = wid & 1;
  int m_l = lane & 15, kgrp = lane >> 4;

  __shared__ char smem[64 * 132 * 4];  // 33792B: conv stage uses 31200B as ushort
  unsigned short* xs = (unsigned short*)smem;
  float* sbuf = (float*)smem;

  f32x4 acc[4][4];
#pragma unroll
  for (int mt = 0; mt < 4; ++mt)
#pragma unroll
    for (int nt = 0; nt < 4; ++nt) acc[mt][nt] = (f32x4)0.f;

  for (int cb = 0; cb < 8; ++cb) {
    __syncthreads();
    // stage rows y-1..y+1, ch cb*32..+31, fp32 -> bf16, transposed [row][px][ch]
    for (int i = tid; i < 1560; i += 256) {
      int k = i & 3;           // ch octet
      int pr = i >> 2;         // 0..389
      int row = pr / 130, px = pr - row * 130;
      int gx = px - 1, gy = y + row - 1;
      bool ok = ((unsigned)gx < 128u) && ((unsigned)gy < 128u);
      const float* xp = x + (((size_t)(b * 256 + cb * 32 + k * 8)) << 14) + gy * 128 + gx;
      u16x8 v;
#pragma unroll
      for (int j = 0; j < 8; ++j) v[j] = ok ? f2bf(xp[(size_t)j << 14]) : 0;
      *(__attribute__((address_space(3))) u16x8*)(&xs[row * XRS + px * XPS + k * 8]) = v;
    }
    __syncthreads();
#pragma unroll
    for (int tap = 0; tap < 9; ++tap) {
      const int kh = tap / 3, kw = tap % 3;
      bf16x8 bfrag[4];
      const unsigned short* wb =
          wT + (((size_t)(cb * 9 + tap) * 256) + ocb * 128 + wx * 64 + m_l) * 32 + kgrp * 8;
#pragma unroll
      for (int nt = 0; nt < 4; ++nt) bfrag[nt] = *(const bf16x8*)(wb + nt * 16 * 32);
#pragma unroll
      for (int mt = 0; mt < 4; ++mt) {
        bf16x8 af = *(__attribute__((address_space(3))) bf16x8*)(
            &xs[kh * XRS + (wy * 64 + mt * 16 + m_l + kw) * XPS + kgrp * 8]);
#pragma unroll
        for (int nt = 0; nt < 4; ++nt)
          acc[mt][nt] = __builtin_amdgcn_mfma_f32_16x16x32_bf16(af, bfrag[nt], acc[mt][nt], 0, 0, 0);
      }
    }
  }

  // BN params per nt (oc fixed per thread per nt)
  float scale4[4], bias4[4];
#pragma unroll
  for (int nt = 0; nt < 4; ++nt) {
    int oc = ocb * 128 + wx * 64 + nt * 16 + m_l;
    float s = bng[oc] * rsqrtf(bnv[oc] + EPS_);
    scale4[nt] = s;
    bias4[nt] = bnb[oc] + (bb[oc] - bnm[oc]) * s;
  }

  // epilogue: 2 chunks of 64 oc; LDS transpose -> coalesced bf16 stores
#pragma unroll
  for (int c = 0; c < 2; ++c) {
    __syncthreads();
    if (wx == c) {
#pragma unroll
      for (int mt = 0; mt < 4; ++mt)
#pragma unroll
        for (int nt = 0; nt < 4; ++nt) {
          f32x4 v = acc[mt][nt];
          float out4[4];
#pragma unroll
          for (int r = 0; r < 4; ++r) {
            float hv = v[r] * scale4[nt] + bias4[nt];
            out4[r] = hv * sigmoidf_(hv);
          }
          int px = wy * 64 + mt * 16 + kgrp * 4;
          float* dst = &sbuf[(nt * 16 + m_l) * 132 + px];
          *(__attribute__((address_space(3))) f32x4*)dst =
              (f32x4){out4[0], out4[1], out4[2], out4[3]};
        }
    }
    __syncthreads();
    // store 64 oc x 128 px, bf16
    int px8 = (tid & 15) * 8, ocl0 = tid >> 4;  // 0..15
#pragma unroll
    for (int i = 0; i < 4; ++i) {
      int ocl = ocl0 + i * 16;
      u16x8 o8;
#pragma unroll
      for (int j = 0; j < 8; ++j) o8[j] = f2bf(sbuf[ocl * 132 + px8 + j]);
      *(u16x8*)(&staticbf[(((size_t)(b * 256 + ocb * 128 + c * 64 + ocl)) << 14) + y * 128 +
                          px8]) = o8;
    }
  }
}

// ---------------------------------------------------------------- CARAFE + blend
// grid: 16 ch-groups x 8 bx x 4 by x 8 b = 4096 blocks; tile 16ch x 32y x 16x
__global__ __launch_bounds__(256) void carafe_blend_kernel(
    const float* __restrict__ x, const float* __restrict__ kern,
    const unsigned short* __restrict__ staticbf, const float* __restrict__ gq,
    float* __restrict__ out) {
  int blk = blockIdx.x;
  int ocg = blk & 15, bx = (blk >> 4) & 7, by = (blk >> 7) & 3, b = blk >> 9;
  __shared__ float xsc[16 * 720];  // 16 ch x 36x20
  for (int i = threadIdx.x; i < 16 * 720; i += 256) {
    int ch = i / 720, r = i - ch * 720;
    int yy = by * 32 + r / 20 - 2, xx = bx * 16 + (r % 20) - 2;
    yy = yy < 0 ? -yy : (yy > 127 ? 254 - yy : yy);
    xx = xx < 0 ? -xx : (xx > 127 ? 254 - xx : xx);
    xsc[i] = x[(((size_t)b * 256 + ocg * 16 + ch) << 14) + yy * 128 + xx];
  }
  __syncthreads();
  int lx = threadIdx.x & 15, y0 = (threadIdx.x >> 4) * 2;
  float gv = gq[b];
  int gy0 = by * 32 + y0, gx = bx * 16 + lx;
  float kv0[25], kv1[25];
  size_t kb = (((size_t)b * 25) << 14) + gy0 * 128 + gx;
#pragma unroll
  for (int n = 0; n < 25; ++n) {
    kv0[n] = kern[kb + ((size_t)n << 14)];
    kv1[n] = kern[kb + ((size_t)n << 14) + 128];
  }
  for (int c = 0; c < 16; ++c) {
    float v[6][5];
#pragma unroll
    for (int r = 0; r < 6; ++r)
#pragma unroll
      for (int j = 0; j < 5; ++j) v[r][j] = xsc[c * 720 + (y0 + r) * 20 + lx + j];
    float car0 = 0.f, car1 = 0.f;
#pragma unroll
    for (int n = 0; n < 25; ++n) {
      int ki = n / 5, kj = n - ki * 5;
      car0 = fmaf(v[ki][kj], kv0[n], car0);
      car1 = fmaf(v[ki + 1][kj], kv1[n], car1);
    }
    size_t ob = (((size_t)(b * 256 + ocg * 16 + c)) << 14) + gy0 * 128 + gx;
    float st0 = bf2f(staticbf[ob]);
    float st1 = bf2f(staticbf[ob + 128]);
    out[ob] = fmaf(gv, car0 - st0, st0);
    out[ob + 128] = fmaf(gv, car1 - st1, st1);
  }
}

// ---------------------------------------------------------------- launcher
extern "C" void kernel_launch(void* const* d_in, const int* in_sizes, int n_in,
                              void* d_out, int out_size, void* d_ws, size_t ws_size,
                              hipStream_t stream) {
  const float* x      = (const float*)d_in[0];
  const float* ke_w1  = (const float*)d_in[1];
  const float* ke_b1  = (const float*)d_in[2];
  const float* ke_bng = (const float*)d_in[3];
  const float* ke_bnb = (const float*)d_in[4];
  const float* ke_bnm = (const float*)d_in[5];
  const float* ke_bnv = (const float*)d_in[6];
  const float* ke_w2  = (const float*)d_in[7];
  const float* ke_b2  = (const float*)d_in[8];
  const float* bs_w   = (const float*)d_in[9];
  const float* bs_b   = (const float*)d_in[10];
  const float* bs_bng = (const float*)d_in[11];
  const float* bs_bnb = (const float*)d_in[12];
  const float* bs_bnm = (const float*)d_in[13];
  const float* bs_bnv = (const float*)d_in[14];
  const float* g_w    = (const float*)d_in[15];
  const float* g_b    = (const float*)d_in[16];
  float* outp = (float*)d_out;

  char* ws = (char*)d_ws;
  float* kern             = (float*)(ws);                       // 13,107,200 B
  float* partial          = (float*)(ws + 13107200);            // 8,192 B
  float* gout             = (float*)(ws + 13115392);            // 32 B
  unsigned short* wT      = (unsigned short*)(ws + 13115648);   // 1,179,648 B
  unsigned short* hbuf    = (unsigned short*)(ws + 14295296);   // 67,108,864 B (reused)
  unsigned short* staticb = hbuf;  // h dead after k1x1; same region reused for static

  wtrans_kernel<<<2304, 256, 0, stream>>>(bs_w, wT);
  gap_partial_kernel<<<2048, 256, 0, stream>>>(x, partial);
  gate_kernel<<<8, 256, 0, stream>>>(partial, g_w, g_b, gout);
  gconv_kernel<<<4096, 256, 0, stream>>>(x, ke_w1, ke_b1, ke_bng, ke_bnb, ke_bnm, ke_bnv, hbuf);
  k1x1_kernel<<<512, 256, 0, stream>>>(hbuf, ke_w2, ke_b2, kern);
  conv_mfma_kernel<<<2048, 256, 0, stream>>>(x, wT, bs_b, bs_bng, bs_bnb, bs_bnm, bs_bnv, staticb);
  carafe_blend_kernel<<<4096, 256, 0, stream>>>(x, kern, staticb, gout, outp);
}

// Round 3
// 1075.444 us; speedup vs baseline: 6.5369x; 1.1716x over previous
//
#include <hip/hip_runtime.h>

#define EPS_ 1e-5f

typedef __attribute__((ext_vector_type(8))) short bf16x8;
typedef __attribute__((ext_vector_type(8))) unsigned short u16x8;
typedef __attribute__((ext_vector_type(4))) float f32x4;
typedef __attribute__((address_space(3))) u16x8 lds_u16x8;
typedef __attribute__((address_space(3))) f32x4 lds_f32x4;

__device__ __forceinline__ float sigmoidf_(float v) { return 1.f / (1.f + __expf(-v)); }

__device__ __forceinline__ unsigned short f2bf(float f) {
  unsigned int u = __float_as_uint(f);
  u += 0x7fff + ((u >> 16) & 1);  // RNE
  return (unsigned short)(u >> 16);
}

__device__ __forceinline__ void cvt8_(u16x8 v, float* f) {
  union { u16x8 s; unsigned int u[4]; } uu;
  uu.s = v;
#pragma unroll
  for (int j = 0; j < 4; ++j) {
    f[2 * j] = __uint_as_float(uu.u[j] << 16);
    f[2 * j + 1] = __uint_as_float(uu.u[j] & 0xffff0000u);
  }
}

// ---------------------------------------------------------------- gate stage 1
__global__ void gap_partial_kernel(const float* __restrict__ x, float* __restrict__ partial) {
  int bc = blockIdx.x;  // 2048
  const float4* p = (const float4*)(x + (size_t)bc * 16384);
  float s = 0.f;
  for (int i = threadIdx.x; i < 4096; i += 256) {
    float4 v = p[i];
    s += (v.x + v.y) + (v.z + v.w);
  }
#pragma unroll
  for (int off = 32; off; off >>= 1) s += __shfl_down(s, off, 64);
  __shared__ float red[4];
  if ((threadIdx.x & 63) == 0) red[threadIdx.x >> 6] = s;
  __syncthreads();
  if (threadIdx.x == 0) partial[bc] = (red[0] + red[1]) + (red[2] + red[3]);
}

// ---------------------------------------------------------------- gate stage 2
__global__ void gate_kernel(const float* __restrict__ partial, const float* __restrict__ gw,
                            const float* __restrict__ gb, float* __restrict__ gout) {
  int b = blockIdx.x, t = threadIdx.x;
  float s = partial[b * 256 + t] * gw[t];
#pragma unroll
  for (int off = 32; off; off >>= 1) s += __shfl_down(s, off, 64);
  __shared__ float red[4];
  if ((t & 63) == 0) red[t >> 6] = s;
  __syncthreads();
  if (t == 0) {
    float tot = (red[0] + red[1]) + (red[2] + red[3]);
    gout[b] = sigmoidf_(tot * (1.f / 16384.f) + gb[0]);
  }
}

// ---------------------------------------------------------------- weight transform
__global__ void wtrans_kernel(const float* __restrict__ w, unsigned short* __restrict__ wT) {
  int n = blockIdx.x * 256 + threadIdx.x;  // 589824
  int c = n & 31, oc = (n >> 5) & 255, t9 = n >> 13;
  int cb = t9 / 9, tap = t9 - cb * 9;
  wT[n] = f2bf(w[(oc * 256 + cb * 32 + c) * 9 + tap]);
}

// ---------------------------------------------------------------- x fp32 NCHW -> xT bf16 NHWC
// grid: 256 px-tiles(64) x 8 b = 2048 blocks
__global__ __launch_bounds__(256) void transpose_kernel(const float* __restrict__ x,
                                                        unsigned short* __restrict__ xT) {
  int blk = blockIdx.x;
  int tile = blk & 255, b = blk >> 8;
  int px0 = tile * 64;
  __shared__ unsigned int tr[64 * 130];  // [px][128 ch-pair words + 2 pad]
  for (int i = threadIdx.x; i < 1024; i += 256) {
    int ch2 = i >> 3, pc = i & 7;
    const float* p0 = x + (((size_t)b * 256 + ch2 * 2) << 14) + px0 + pc * 8;
    const float4* a4 = (const float4*)p0;
    const float4* b4 = (const float4*)(p0 + 16384);
    float4 a0 = a4[0], a1 = a4[1], b0 = b4[0], b1 = b4[1];
    float fa[8] = {a0.x, a0.y, a0.z, a0.w, a1.x, a1.y, a1.z, a1.w};
    float fb[8] = {b0.x, b0.y, b0.z, b0.w, b1.x, b1.y, b1.z, b1.w};
#pragma unroll
    for (int j = 0; j < 8; ++j) {
      unsigned int w = (unsigned int)f2bf(fa[j]) | ((unsigned int)f2bf(fb[j]) << 16);
      tr[(pc * 8 + j) * 130 + ch2] = w;
    }
  }
  __syncthreads();
  for (int i = threadIdx.x; i < 2048; i += 256) {
    int px = i >> 5, kc = i & 31;
    uint4 v = *(uint4*)&tr[px * 130 + kc * 4];
    *(uint4*)(xT + ((((size_t)b << 14)) + px0 + px) * 256 + kc * 8) = v;
  }
}

// ------------------- fused: grouped conv + BN + SiLU + 1x1 + softmax -> kern
// grid: 64 tiles(16x16) x 8 b = 512 blocks. h never materialized.
__global__ __launch_bounds__(256) void kernelgen_kernel(
    const unsigned short* __restrict__ xT, const float* __restrict__ w1,
    const float* __restrict__ b1, const float* __restrict__ bng, const float* __restrict__ bnb,
    const float* __restrict__ bnm, const float* __restrict__ bnv, const float* __restrict__ w2,
    const float* __restrict__ b2, float* __restrict__ kern) {
  int blk = blockIdx.x;
  int t = blk & 63, b = blk >> 6;
  int px0 = (t & 7) * 16, py0 = (t >> 3) * 16;
  int lx = threadIdx.x & 15, ly = threadIdx.x >> 4;
  __shared__ unsigned short xs[324 * 40];  // [18x18 px][32 ch + 8 pad]
  float acc[25];
#pragma unroll
  for (int n = 0; n < 25; ++n) acc[n] = b2[n];

  for (int gq = 0; gq < 8; ++gq) {  // 4 groups (32 ch) per round
    __syncthreads();
    for (int i = threadIdx.x; i < 1296; i += 256) {
      int s = i & 3, p = i >> 2;
      int yy = py0 + p / 18 - 1, xx = px0 + (p % 18) - 1;
      u16x8 v = (u16x8)(unsigned short)0;
      if (((unsigned)yy < 128u) && ((unsigned)xx < 128u))
        v = *(const u16x8*)(xT + (((size_t)(b << 14)) + yy * 128 + xx) * 256 + gq * 32 + s * 8);
      *(lds_u16x8*)(&xs[p * 40 + s * 8]) = v;
    }
    __syncthreads();
#pragma unroll
    for (int s = 0; s < 4; ++s) {
      int g = gq * 4 + s;
      float xf[72];  // [tap][ic]
#pragma unroll
      for (int tp = 0; tp < 9; ++tp) {
        u16x8 v = *(lds_u16x8*)(&xs[((ly + tp / 3) * 18 + lx + tp % 3) * 40 + s * 8]);
        cvt8_(v, &xf[tp * 8]);
      }
#pragma unroll
      for (int o = 0; o < 8; ++o) {
        int c = g * 8 + o;
        float h = b1[c];
        const float* wp = w1 + c * 72;  // uniform -> s_load
#pragma unroll
        for (int ic = 0; ic < 8; ++ic)
#pragma unroll
          for (int tp = 0; tp < 9; ++tp) h = fmaf(xf[tp * 8 + ic], wp[ic * 9 + tp], h);
        float scale = bng[c] * rsqrtf(bnv[c] + EPS_);
        float hb = (h - bnm[c]) * scale + bnb[c];
        float sv = hb * sigmoidf_(hb);
#pragma unroll
        for (int n = 0; n < 25; ++n) acc[n] = fmaf(sv, w2[n * 256 + c], acc[n]);
      }
    }
  }
  float m = acc[0];
#pragma unroll
  for (int n = 1; n < 25; ++n) m = fmaxf(m, acc[n]);
  float sum = 0.f;
#pragma unroll
  for (int n = 0; n < 25; ++n) { acc[n] = __expf(acc[n] - m); sum += acc[n]; }
  float inv = 1.f / sum;
  size_t base = (((size_t)b * 25) << 14) + (py0 + ly) * 128 + px0 + lx;
#pragma unroll
  for (int n = 0; n < 25; ++n) kern[base + ((size_t)n << 14)] = acc[n] * inv;
}

// ---------------------------------------------------------------- dense conv via MFMA
// M=128 px (one row) x N=128 oc; K = 8 cb x 9 taps x 32 ch. Writes fp32 static to out.
#define XPS 40
#define XRS (130 * XPS)
__global__ __launch_bounds__(256) void conv_mfma_kernel(
    const unsigned short* __restrict__ xT, const unsigned short* __restrict__ wT,
    const float* __restrict__ bb, const float* __restrict__ bng, const float* __restrict__ bnb,
    const float* __restrict__ bnm, const float* __restrict__ bnv, float* __restrict__ out) {
  int blk = blockIdx.x;
  int ocb = blk & 1, y = (blk >> 1) & 127, b = blk >> 8;
  int tid = threadIdx.x, lane = tid & 63, wid = tid >> 6;
  int wy = wid >> 1, wx = wid & 1;
  int m_l = lane & 15, kgrp = lane >> 4;

  __shared__ char smem[64 * 132 * 4];  // conv: 31200B as ushort; epilogue: fp32
  unsigned short* xs = (unsigned short*)smem;
  float* sbuf = (float*)smem;

  f32x4 acc[4][4];
#pragma unroll
  for (int mt = 0; mt < 4; ++mt)
#pragma unroll
    for (int nt = 0; nt < 4; ++nt) acc[mt][nt] = (f32x4)0.f;

  for (int cb = 0; cb < 8; ++cb) {
    __syncthreads();
    for (int i = tid; i < 1560; i += 256) {
      int k = i & 3, pr = i >> 2;
      int row = pr / 130, px = pr - row * 130;
      int gx = px - 1, gy = y + row - 1;
      u16x8 v = (u16x8)(unsigned short)0;
      if (((unsigned)gx < 128u) && ((unsigned)gy < 128u))
        v = *(const u16x8*)(xT + (((size_t)(b << 14)) + gy * 128 + gx) * 256 + cb * 32 + k * 8);
      *(lds_u16x8*)(&xs[row * XRS + px * XPS + k * 8]) = v;
    }
    __syncthreads();
#pragma unroll
    for (int tap = 0; tap < 9; ++tap) {
      const int kh = tap / 3, kw = tap % 3;
      bf16x8 bfrag[4];
      const unsigned short* wb =
          wT + (((size_t)(cb * 9 + tap) * 256) + ocb * 128 + wx * 64 + m_l) * 32 + kgrp * 8;
#pragma unroll
      for (int nt = 0; nt < 4; ++nt) bfrag[nt] = *(const bf16x8*)(wb + nt * 16 * 32);
#pragma unroll
      for (int mt = 0; mt < 4; ++mt) {
        bf16x8 af = *(__attribute__((address_space(3))) bf16x8*)(
            &xs[kh * XRS + (wy * 64 + mt * 16 + m_l + kw) * XPS + kgrp * 8]);
#pragma unroll
        for (int nt = 0; nt < 4; ++nt)
          acc[mt][nt] = __builtin_amdgcn_mfma_f32_16x16x32_bf16(af, bfrag[nt], acc[mt][nt], 0, 0, 0);
      }
    }
  }

  float scale4[4], bias4[4];
#pragma unroll
  for (int nt = 0; nt < 4; ++nt) {
    int oc = ocb * 128 + wx * 64 + nt * 16 + m_l;
    float s = bng[oc] * rsqrtf(bnv[oc] + EPS_);
    scale4[nt] = s;
    bias4[nt] = bnb[oc] + (bb[oc] - bnm[oc]) * s;
  }

#pragma unroll
  for (int c = 0; c < 2; ++c) {
    __syncthreads();
    if (wx == c) {
#pragma unroll
      for (int mt = 0; mt < 4; ++mt)
#pragma unroll
        for (int nt = 0; nt < 4; ++nt) {
          f32x4 v = acc[mt][nt];
          float o4[4];
#pragma unroll
          for (int r = 0; r < 4; ++r) {
            float hv = v[r] * scale4[nt] + bias4[nt];
            o4[r] = hv * sigmoidf_(hv);
          }
          int px = wy * 64 + mt * 16 + kgrp * 4;
          *(lds_f32x4*)(&sbuf[(nt * 16 + m_l) * 132 + px]) = (f32x4){o4[0], o4[1], o4[2], o4[3]};
        }
    }
    __syncthreads();
    int kc = tid & 31, oc0 = tid >> 5;
#pragma unroll
    for (int i = 0; i < 8; ++i) {
      int ocl = oc0 + i * 8;
      f32x4 v = *(lds_f32x4*)(&sbuf[ocl * 132 + kc * 4]);
      *(f32x4*)(out + (((size_t)(b * 256 + ocb * 128 + c * 64 + ocl)) << 14) + y * 128 + kc * 4) = v;
    }
  }
}

// ---------------------------------------------------------------- CARAFE + blend (RMW on out)
// grid: 16 ch-groups x 8 bx x 4 by x 8 b = 4096 blocks; tile 16ch x 32y x 16x
__global__ __launch_bounds__(256) void carafe_blend_kernel(
    const unsigned short* __restrict__ xT, const float* __restrict__ kern,
    const float* __restrict__ gq, float* __restrict__ out) {
  int blk = blockIdx.x;
  int ocg = blk & 15, bx = (blk >> 4) & 7, by = (blk >> 7) & 3, b = blk >> 9;
  __shared__ unsigned short xc[720 * 16];  // [36x20 px][16 ch]
  for (int i = threadIdx.x; i < 1440; i += 256) {
    int half = i & 1, p = i >> 1;
    int py = p / 20, pxx = p - py * 20;
    int yy = by * 32 + py - 2, xx = bx * 16 + pxx - 2;
    yy = yy < 0 ? -yy : (yy > 127 ? 254 - yy : yy);
    xx = xx < 0 ? -xx : (xx > 127 ? 254 - xx : xx);
    *(lds_u16x8*)(&xc[p * 16 + half * 8]) =
        *(const u16x8*)(xT + (((size_t)(b << 14)) + yy * 128 + xx) * 256 + ocg * 16 + half * 8);
  }
  __syncthreads();
  int lx = threadIdx.x & 15, y0 = (threadIdx.x >> 4) * 2;
  float gv = gq[b];
  int gy0 = by * 32 + y0, gx = bx * 16 + lx;
  float kv0[25], kv1[25];
  size_t kb = (((size_t)b * 25) << 14) + gy0 * 128 + gx;
#pragma unroll
  for (int n = 0; n < 25; ++n) {
    kv0[n] = kern[kb + ((size_t)n << 14)];
    kv1[n] = kern[kb + ((size_t)n << 14) + 128];
  }
  float car0[16], car1[16];
#pragma unroll
  for (int c = 0; c < 16; ++c) { car0[c] = 0.f; car1[c] = 0.f; }
#pragma unroll
  for (int n = 0; n < 25; ++n) {
    int ki = n / 5, kj = n - ki * 5;
    int p0 = (y0 + ki) * 20 + lx + kj;
    float f0[16], f1[16];
    cvt8_(*(lds_u16x8*)(&xc[p0 * 16]), &f0[0]);
    cvt8_(*(lds_u16x8*)(&xc[p0 * 16 + 8]), &f0[8]);
    cvt8_(*(lds_u16x8*)(&xc[(p0 + 20) * 16]), &f1[0]);
    cvt8_(*(lds_u16x8*)(&xc[(p0 + 20) * 16 + 8]), &f1[8]);
#pragma unroll
    for (int c = 0; c < 16; ++c) {
      car0[c] = fmaf(f0[c], kv0[n], car0[c]);
      car1[c] = fmaf(f1[c], kv1[n], car1[c]);
    }
  }
#pragma unroll
  for (int c = 0; c < 16; ++c) {
    size_t ob = (((size_t)(b * 256 + ocg * 16 + c)) << 14) + gy0 * 128 + gx;
    float st0 = out[ob], st1 = out[ob + 128];
    out[ob] = fmaf(gv, car0[c] - st0, st0);
    out[ob + 128] = fmaf(gv, car1[c] - st1, st1);
  }
}

// ---------------------------------------------------------------- launcher
extern "C" void kernel_launch(void* const* d_in, const int* in_sizes, int n_in,
                              void* d_out, int out_size, void* d_ws, size_t ws_size,
                              hipStream_t stream) {
  const float* x      = (const float*)d_in[0];
  const float* ke_w1  = (const float*)d_in[1];
  const float* ke_b1  = (const float*)d_in[2];
  const float* ke_bng = (const float*)d_in[3];
  const float* ke_bnb = (const float*)d_in[4];
  const float* ke_bnm = (const float*)d_in[5];
  const float* ke_bnv = (const float*)d_in[6];
  const float* ke_w2  = (const float*)d_in[7];
  const float* ke_b2  = (const float*)d_in[8];
  const float* bs_w   = (const float*)d_in[9];
  const float* bs_b   = (const float*)d_in[10];
  const float* bs_bng = (const float*)d_in[11];
  const float* bs_bnb = (const float*)d_in[12];
  const float* bs_bnm = (const float*)d_in[13];
  const float* bs_bnv = (const float*)d_in[14];
  const float* g_w    = (const float*)d_in[15];
  const float* g_b    = (const float*)d_in[16];
  float* outp = (float*)d_out;

  char* ws = (char*)d_ws;
  float* kern        = (float*)(ws);                      // 13,107,200 B
  float* partial     = (float*)(ws + 13107200);           // 8,192 B
  float* gout        = (float*)(ws + 13115392);           // 256 B
  unsigned short* wT = (unsigned short*)(ws + 13115648);  // 1,179,648 B
  unsigned short* xT = (unsigned short*)(ws + 14295296);  // 67,108,864 B -> total 81,404,160

  wtrans_kernel<<<2304, 256, 0, stream>>>(bs_w, wT);
  gap_partial_kernel<<<2048, 256, 0, stream>>>(x, partial);
  gate_kernel<<<8, 256, 0, stream>>>(partial, g_w, g_b, gout);
  transpose_kernel<<<2048, 256, 0, stream>>>(x, xT);
  kernelgen_kernel<<<512, 256, 0, stream>>>(xT, ke_w1, ke_b1, ke_bng, ke_bnb, ke_bnm, ke_bnv,
                                            ke_w2, ke_b2, kern);
  conv_mfma_kernel<<<2048, 256, 0, stream>>>(xT, wT, bs_b, bs_bng, bs_bnb, bs_bnm, bs_bnv, outp);
  carafe_blend_kernel<<<4096, 256, 0, stream>>>(xT, kern, gout, outp);
}